// Round 12
// baseline (540.506 us; speedup 1.0000x reference)
//
#include <hip/hip_runtime.h>
#include <hip/hip_bf16.h>

#define TT 2048
#define BB 512
#define HH 32
#define NPAIR (TT * BB)
#define PSTRIDE (BB * HH)   // elements per t-slice of P = 16384

// Pin a value into a live VGPR (R9-proven variant, no memory clobber).
#define PIN(x) asm volatile("" : "+v"(x))

// Hardware-fused rotate-and-FMA: acc += row_ror:N(src) * w  (one VOP2 DPP inst).
// This is the whole point of R12: the compiler emitted separate v_mov_b32_dpp
// (~6 cyc each, ~90 cyc/step of pure rotation overhead) because each rotation had
// two consumers. Inline asm forces the fused form with exactly one consumer.
#define FMROR(acc, src, w, N)                                                   \
    asm volatile("v_fmac_f32_dpp %0, %1, %2 row_ror:" #N                        \
                 " row_mask:0xf bank_mask:0xf"                                  \
                 : "+v"(acc) : "v"(src), "v"(w))

// tanh(u) = 1 - 2/(1+e^{2u}); exact at both saturations.
__device__ __forceinline__ float fast_tanh(float u) {
    float e = exp2f(u * 2.88539008177792681f);          // e^{2u} via v_exp_f32
    return fmaf(__builtin_amdgcn_rcpf(e + 1.0f), -2.0f, 1.0f);
}

// ---------------- Pass 1: P[t][row][j] = b[j] + emb[x[t,row]] @ Wx[:,j]  (bf16 out) ----
__global__ __launch_bounds__(256) void precompute_v11(
        const int* __restrict__ x, const float* __restrict__ emb,
        const float* __restrict__ W_rnn, const float* __restrict__ b_rnn,
        __hip_bfloat16* __restrict__ P) {
    const int tid = threadIdx.x;
    const int jj  = tid & 31;
    const int l   = tid & 63;
    const int grp = tid >> 5;
    const int g   = (blockIdx.x * 256 + tid) >> 5;
    const int pair0 = g * 16;

    __shared__ float stage[8][16][HH];

    float wx[32];
#pragma unroll
    for (int k = 0; k < 32; ++k) wx[k] = W_rnn[k * HH + jj];
    const float bj = b_rnn[jj];

    const int idxv  = x[pair0 + (jj & 15)];
    const int bbase = (l & 32) * 4;

    float ev[16];
#pragma unroll
    for (int i = 0; i < 16; ++i) {
        int pi = __builtin_amdgcn_ds_bpermute(bbase + 4 * i, idxv);
        ev[i] = emb[(size_t)pi * HH + jj];
    }
#pragma unroll
    for (int i = 0; i < 16; ++i)
        stage[grp][i][jj] = ev[i];

#pragma unroll 4
    for (int i = 0; i < 16; ++i) {
        const float4* sp = (const float4*)&stage[grp][i][0];
        float u0 = bj, u1 = 0.f, u2 = 0.f, u3 = 0.f;
#pragma unroll
        for (int q = 0; q < 8; ++q) {
            float4 e = sp[q];
            u0 = fmaf(e.x, wx[4*q+0], u0);
            u1 = fmaf(e.y, wx[4*q+1], u1);
            u2 = fmaf(e.z, wx[4*q+2], u2);
            u3 = fmaf(e.w, wx[4*q+3], u3);
        }
        P[(size_t)(pair0 + i) * HH + jj] = __float2bfloat16((u0 + u1) + (u2 + u3));
    }
}

// ---------------- Pass 2: fused-DPP scan, 4 rows/wave, lo/hi split (R8 layout) ---------
// Lane l: i=l&15 (position in 16-lane row), r=l>>4 (row in wave). Lane owns h[i] (lo)
// and h[i+16] (hi) => whole h@Wh dot is row-local rotation; ZERO DS ops in the chain.
// All 60 rotated terms are v_fmac_f32_dpp (fused rotate+FMA). DPP-read-after-VALU-write
// hazard (h written by tanh) covered by s_nop 1 tied to h at step start.
__global__ __launch_bounds__(64, 1) void rnn_seq_v12(
        const __hip_bfloat16* __restrict__ P, const float* __restrict__ W_rnn,
        const float* __restrict__ W_cls, const float* __restrict__ b_cls,
        float* __restrict__ out) {
    const int l = threadIdx.x;
    const int i = l & 15;
    const int r = l >> 4;

    // Direction probe (validated R6-R11: absmax 0.0): d=+1 if ror:1 pulls from lane i+1.
    int rt = __builtin_amdgcn_mov_dpp(i, 0x121, 0xF, 0xF, false);
    const int d = (rt == ((i + 1) & 15)) ? 1 : -1;

    // Weight tables in rotation order (R8-validated mapping).
    float wA[16], wB[16], wC[16], wD[16];
#pragma unroll
    for (int o = 0; o < 16; ++o) {
        const int rot = (i + d * o) & 15;
        wA[o] = W_rnn[(HH + rot) * HH + i];             // h_lo -> u_lo
        wB[o] = W_rnn[(HH + 16 + rot) * HH + i];        // h_hi -> u_lo
        wC[o] = W_rnn[(HH + rot) * HH + (i + 16)];      // h_lo -> u_hi
        wD[o] = W_rnn[(HH + 16 + rot) * HH + (i + 16)]; // h_hi -> u_hi
    }
#pragma unroll
    for (int o = 0; o < 16; ++o) { PIN(wA[o]); PIN(wB[o]); PIN(wC[o]); PIN(wD[o]); }

    // bf16 P, lo at +0 / hi at +16 of row (blk*4+r).
    const __hip_bfloat16* gp = P + (size_t)(blockIdx.x * 4 + r) * HH + i;

    float pAl[8], pAh[8], pBl[8], pBh[8];
#pragma unroll
    for (int t = 0; t < 8; ++t) {
        pAl[t] = __bfloat162float(gp[(size_t)t * PSTRIDE]);
        pAh[t] = __bfloat162float(gp[(size_t)t * PSTRIDE + 16]);
    }

    float h_lo = 0.0f, h_hi = 0.0f;

    auto step = [&](float plo, float phi) {
        // DPP hazard guard: h_lo/h_hi were just written by VALU (tanh); a DPP read
        // needs 2 wait states. Tie the nop to h so it can't drift before the write.
        asm volatile("s_nop 1" : "+v"(h_lo), "+v"(h_hi));
        float la[4], ha[4];
        la[0] = fmaf(h_lo, wA[0], plo);   // o=0 terms: no rotation
        la[1] = h_hi * wB[0];
        la[2] = 0.0f; la[3] = 0.0f;
        ha[0] = fmaf(h_lo, wC[0], phi);
        ha[1] = h_hi * wD[0];
        ha[2] = 0.0f; ha[3] = 0.0f;
#define OFFS(N)                                                                 \
        FMROR(la[(N) & 3], h_lo, wA[N], N);                                     \
        FMROR(la[((N) + 2) & 3], h_hi, wB[N], N);                               \
        FMROR(ha[(N) & 3], h_lo, wC[N], N);                                     \
        FMROR(ha[((N) + 2) & 3], h_hi, wD[N], N);
        OFFS(1)  OFFS(2)  OFFS(3)  OFFS(4)  OFFS(5)
        OFFS(6)  OFFS(7)  OFFS(8)  OFFS(9)  OFFS(10)
        OFFS(11) OFFS(12) OFFS(13) OFFS(14) OFFS(15)
#undef OFFS
        h_lo = fast_tanh((la[0] + la[1]) + (la[2] + la[3]));
        h_hi = fast_tanh((ha[0] + ha[1]) + (ha[2] + ha[3]));
    };

#pragma unroll 1
    for (int e = 0; e < TT / 16; ++e) {
        const int tB = e * 16 + 8;
#pragma unroll
        for (int t = 0; t < 8; ++t) {
            pBl[t] = __bfloat162float(gp[(size_t)(tB + t) * PSTRIDE]);
            pBh[t] = __bfloat162float(gp[(size_t)(tB + t) * PSTRIDE + 16]);
        }
#pragma unroll
        for (int t = 0; t < 8; ++t) { PIN(pAl[t]); PIN(pAh[t]); }
#pragma unroll
        for (int s = 0; s < 8; ++s) step(pAl[s], pAh[s]);

        int tA = e * 16 + 16;
        if (tA > TT - 8) tA = TT - 8;   // tail reload redundant but in-bounds
#pragma unroll
        for (int t = 0; t < 8; ++t) {
            pAl[t] = __bfloat162float(gp[(size_t)(tA + t) * PSTRIDE]);
            pAh[t] = __bfloat162float(gp[(size_t)(tA + t) * PSTRIDE + 16]);
        }
#pragma unroll
        for (int t = 0; t < 8; ++t) { PIN(pBl[t]); PIN(pBh[t]); }
#pragma unroll
        for (int s = 0; s < 8; ++s) step(pBl[s], pBh[s]);
    }

    // Epilogue (R8-validated): y = h @ W_cls + b_cls for 4 rows.
    __shared__ float hf[4 * HH];
    hf[r * HH + i]      = h_lo;
    hf[r * HH + i + 16] = h_hi;
    if (l < 20) {
        const int rr = l / 5, c = l % 5;
        float acc = b_cls[c];
#pragma unroll
        for (int k = 0; k < 32; ++k)
            acc = fmaf(hf[rr * HH + k], W_cls[k * 5 + c], acc);
        out[(blockIdx.x * 4 + rr) * 5 + c] = acc;
    }
}

// ---------------- Fallback (fused) for tiny workspace ----------------------------------
__device__ __forceinline__ float rnn_step_fb(const float4 xt[8], const float wx[32],
                                             const float wh[32], float bj,
                                             float* hrow, int lane) {
    float u0 = 0.f, u1 = 0.f, u2 = 0.f, u3 = 0.f;
#pragma unroll
    for (int q = 0; q < 8; ++q) {
        u0 = fmaf(xt[q].x, wx[4*q+0], u0);
        u1 = fmaf(xt[q].y, wx[4*q+1], u1);
        u2 = fmaf(xt[q].z, wx[4*q+2], u2);
        u3 = fmaf(xt[q].w, wx[4*q+3], u3);
    }
    const float4* hp = (const float4*)hrow;
#pragma unroll
    for (int q = 0; q < 8; ++q) {
        float4 hv = hp[q];
        u0 = fmaf(hv.x, wh[4*q+0], u0);
        u1 = fmaf(hv.y, wh[4*q+1], u1);
        u2 = fmaf(hv.z, wh[4*q+2], u2);
        u3 = fmaf(hv.w, wh[4*q+3], u3);
    }
    float hn = fast_tanh(bj + ((u0 + u1) + (u2 + u3)));
    hrow[lane] = hn;
    return hn;
}

__global__ __launch_bounds__(64, 1) void rnn_seq_kernel(
        const int* __restrict__ x, const float* __restrict__ emb,
        const float* __restrict__ W_rnn, const float* __restrict__ b_rnn,
        const float* __restrict__ W_cls, const float* __restrict__ b_cls,
        float* __restrict__ out) {
    const int lane = threadIdx.x & 31;
    const int grp  = threadIdx.x >> 5;
    const int row  = blockIdx.x * 2 + grp;
    __shared__ float hbuf[2][HH];
    float wx[32], wh[32];
#pragma unroll
    for (int k = 0; k < 32; ++k) {
        wx[k] = W_rnn[k * HH + lane];
        wh[k] = W_rnn[(HH + k) * HH + lane];
    }
    const float bj = b_rnn[lane];
    hbuf[grp][lane] = 0.0f;
    float* hrow = &hbuf[grp][0];
    int i1 = x[1 * BB + row];
    float4 xcur[8], xnxt[8];
    {
        int i0 = x[0 * BB + row];
        const float4* ep = (const float4*)(emb + (size_t)i0 * HH);
#pragma unroll
        for (int q = 0; q < 8; ++q) xcur[q] = ep[q];
    }
    for (int t = 0; t < TT; t += 2) {
        int i2 = x[min(t + 2, TT - 1) * BB + row];
        {
            const float4* ep = (const float4*)(emb + (size_t)i1 * HH);
#pragma unroll
            for (int q = 0; q < 8; ++q) xnxt[q] = ep[q];
        }
        rnn_step_fb(xcur, wx, wh, bj, hrow, lane);
        i1 = x[min(t + 3, TT - 1) * BB + row];
        {
            const float4* ep = (const float4*)(emb + (size_t)i2 * HH);
#pragma unroll
            for (int q = 0; q < 8; ++q) xcur[q] = ep[q];
        }
        rnn_step_fb(xnxt, wx, wh, bj, hrow, lane);
    }
    if (lane < 5) {
        float acc = b_cls[lane];
#pragma unroll
        for (int k = 0; k < 32; ++k)
            acc = fmaf(hrow[k], W_cls[k * 5 + lane], acc);
        out[row * 5 + lane] = acc;
    }
}

extern "C" void kernel_launch(void* const* d_in, const int* in_sizes, int n_in,
                              void* d_out, int out_size, void* d_ws, size_t ws_size,
                              hipStream_t stream) {
    const int*   x     = (const int*)d_in[0];
    const float* emb   = (const float*)d_in[1];
    const float* W_rnn = (const float*)d_in[2];
    const float* b_rnn = (const float*)d_in[3];
    const float* W_cls = (const float*)d_in[4];
    const float* b_cls = (const float*)d_in[5];
    float* out = (float*)d_out;

    const size_t need16 = (size_t)NPAIR * HH * 2;   // 64 MiB (bf16 P)
    if (ws_size >= need16) {
        __hip_bfloat16* P = (__hip_bfloat16*)d_ws;
        const int pre_blocks = NPAIR / (16 * 8);    // 8192 blocks x 256 thr
        precompute_v11<<<pre_blocks, 256, 0, stream>>>(x, emb, W_rnn, b_rnn, P);
        rnn_seq_v12<<<BB / 4, 64, 0, stream>>>(P, W_rnn, W_cls, b_cls, out);
    } else {
        rnn_seq_kernel<<<BB / 2, 64, 0, stream>>>(x, emb, W_rnn, b_rnn, W_cls, b_cls, out);
    }
}

// Round 13
// 371.359 us; speedup vs baseline: 1.4555x; 1.4555x over previous
//
#include <hip/hip_runtime.h>
#include <hip/hip_bf16.h>

#define TT 2048
#define BB 512
#define HH 32
#define NPAIR (TT * BB)
#define PSTRIDE (BB * HH)   // elements per t-slice of P = 16384
#define CSC 2.88539008177792681f   // 2*log2(e), folded into W/b/P

// Pin a value into a live VGPR (R9-proven variant, no memory clobber).
#define PIN(x) asm volatile("" : "+v"(x))

// Inputs pre-scaled by CSC => tanh(u) = 1 - 2/(1+2^u'), u' = CSC*u arrives ready.
__device__ __forceinline__ float fast_tanh_pre(float u) {
    float e = exp2f(u);
    return fmaf(__builtin_amdgcn_rcpf(e + 1.0f), -2.0f, 1.0f);
}
// Unscaled variant for the fallback kernel.
__device__ __forceinline__ float fast_tanh(float u) {
    float e = exp2f(u * CSC);
    return fmaf(__builtin_amdgcn_rcpf(e + 1.0f), -2.0f, 1.0f);
}

// DPP row-rotate by N within each 16-lane row.
template <int N>
__device__ __forceinline__ float dpp_ror(float v) {
    return __int_as_float(__builtin_amdgcn_mov_dpp(
        __float_as_int(v), 0x120 | N, 0xF, 0xF, false));
}
// lane xor 16 within each 32-lane group (BitMode: xor=16, and=0x1F).
__device__ __forceinline__ float swz_x16(float v) {
    return __int_as_float(__builtin_amdgcn_ds_swizzle(__float_as_int(v), 0x401F));
}

__device__ __forceinline__ short f2bf(float f) {
    __hip_bfloat16 h = __float2bfloat16(f);
    return *reinterpret_cast<short*>(&h);
}

// ---------------- Pass 1: MFMA precompute. P[t][row][:] = CSC*(b + emb[x]@Wx) ---------
// One wave per 16 pairs, ZERO LDS (the v5/v11 pre spent ~100us, ~5x its floor, on
// broadcast ds_read_b128 + per-element VALU matvec across 128 waves/CU sharing one DS
// pipe). Here: lane m=l&15 gathers its row's 8-float k-slice (A-frag layout
// A[m=lane&15][k=quad*8+j], m89/m120-verified), Wx as B-frag, 2x mfma 16x16x32 bf16,
// C layout col=lane&15,row=quad*4+reg (m89-verified), bf16 stores.
typedef __attribute__((ext_vector_type(8))) short bf16x8;
typedef __attribute__((ext_vector_type(4))) float f32x4;

__global__ __launch_bounds__(256) void precompute_mfma(
        const int* __restrict__ x, const float* __restrict__ emb,
        const float* __restrict__ W_rnn, const float* __restrict__ b_rnn,
        __hip_bfloat16* __restrict__ P) {
    const int l  = threadIdx.x & 63;
    const int wv = (blockIdx.x * 256 + threadIdx.x) >> 6;   // global wave id
    const int pair0 = wv * 16;
    const int m  = l & 15;
    const int kb = (l >> 4) * 8;          // k-slice base for A/B fragments

    // B fragments: Wx (pre-scaled by CSC), cols m and m+16.
    bf16x8 bf0, bf1;
#pragma unroll
    for (int j = 0; j < 8; ++j) {
        bf0[j] = f2bf(CSC * W_rnn[(kb + j) * HH + m]);
        bf1[j] = f2bf(CSC * W_rnn[(kb + j) * HH + m + 16]);
    }

    // A fragment: gather 16 rows; lane m reads row idx_m, elements kb..kb+7.
    const int idx = x[pair0 + m];
    const float4* ep = (const float4*)(emb + (size_t)idx * HH + kb);
    float4 e0 = ep[0], e1 = ep[1];
    bf16x8 af;
    af[0] = f2bf(e0.x); af[1] = f2bf(e0.y); af[2] = f2bf(e0.z); af[3] = f2bf(e0.w);
    af[4] = f2bf(e1.x); af[5] = f2bf(e1.y); af[6] = f2bf(e1.z); af[7] = f2bf(e1.w);

    // C init = scaled bias (broadcast down the M rows this lane holds).
    const float bn0 = CSC * b_rnn[m], bn1 = CSC * b_rnn[m + 16];
    f32x4 c0 = {bn0, bn0, bn0, bn0};
    f32x4 c1 = {bn1, bn1, bn1, bn1};
    c0 = __builtin_amdgcn_mfma_f32_16x16x32_bf16(af, bf0, c0, 0, 0, 0);
    c1 = __builtin_amdgcn_mfma_f32_16x16x32_bf16(af, bf1, c1, 0, 0, 0);

    // Store: row = (l>>4)*4 + reg, col = m / m+16.
#pragma unroll
    for (int reg = 0; reg < 4; ++reg) {
        const int row = (l >> 4) * 4 + reg;
        P[(size_t)(pair0 + row) * HH + m]      = __float2bfloat16(c0[reg]);
        P[(size_t)(pair0 + row) * HH + m + 16] = __float2bfloat16(c1[reg]);
    }
}

// ---------------- Pass 2: k-split scan (R11-exact; weights pre-scaled) -----------------
__global__ __launch_bounds__(64, 1) void rnn_seq_v13(
        const __hip_bfloat16* __restrict__ P, const float* __restrict__ W_rnn,
        const float* __restrict__ W_cls, const float* __restrict__ b_cls,
        float* __restrict__ out) {
    const int l = threadIdx.x;
    const int i = l & 15;
    const int q = (l >> 4) & 1;

    // Direction probe (validated R6-R12: absmax 0.0).
    int rt = __builtin_amdgcn_mov_dpp(i, 0x121, 0xF, 0xF, false);
    const int d = (rt == ((i + 1) & 15)) ? 1 : -1;

    float wKeep[16], wSend[16];
#pragma unroll
    for (int o = 0; o < 16; ++o) {
        const int k = q * 16 + ((i + d * o) & 15);
        wKeep[o] = CSC * W_rnn[(HH + k) * HH + (q * 16 + i)];
        wSend[o] = CSC * W_rnn[(HH + k) * HH + ((q ^ 1) * 16 + i)];
    }
#pragma unroll
    for (int o = 0; o < 16; ++o) { PIN(wKeep[o]); PIN(wSend[o]); }

    const __hip_bfloat16* gp = P + (size_t)blockIdx.x * 64 + l;

    float pA[8], pB[8];
#pragma unroll
    for (int t = 0; t < 8; ++t)
        pA[t] = __bfloat162float(gp[(size_t)t * PSTRIDE]);

    float h = 0.0f;

    auto step = [&](float p) {
        float rot[16];
        rot[0] = h;
        rot[1] = dpp_ror<1>(h);
        rot[2] = dpp_ror<2>(h);
        rot[3] = dpp_ror<3>(h);
#pragma unroll
        for (int m = 1; m < 4; ++m) {
            rot[4*m+0] = dpp_ror<4>(rot[4*m-4]);
            rot[4*m+1] = dpp_ror<4>(rot[4*m-3]);
            rot[4*m+2] = dpp_ror<4>(rot[4*m-2]);
            rot[4*m+3] = dpp_ror<4>(rot[4*m-1]);
        }
        float s0 = rot[0] * wSend[0], s1 = rot[1] * wSend[1];
        float s2 = rot[2] * wSend[2], s3 = rot[3] * wSend[3];
#pragma unroll
        for (int m = 1; m < 4; ++m) {
            s0 = fmaf(rot[4*m+0], wSend[4*m+0], s0);
            s1 = fmaf(rot[4*m+1], wSend[4*m+1], s1);
            s2 = fmaf(rot[4*m+2], wSend[4*m+2], s2);
            s3 = fmaf(rot[4*m+3], wSend[4*m+3], s3);
        }
        float send = (s0 + s1) + (s2 + s3);
        float recv = swz_x16(send);
        float k0 = fmaf(rot[0], wKeep[0], p), k1 = rot[1] * wKeep[1];
        float k2 = rot[2] * wKeep[2],         k3 = rot[3] * wKeep[3];
#pragma unroll
        for (int m = 1; m < 4; ++m) {
            k0 = fmaf(rot[4*m+0], wKeep[4*m+0], k0);
            k1 = fmaf(rot[4*m+1], wKeep[4*m+1], k1);
            k2 = fmaf(rot[4*m+2], wKeep[4*m+2], k2);
            k3 = fmaf(rot[4*m+3], wKeep[4*m+3], k3);
        }
        float u = ((k0 + k1) + (k2 + k3)) + recv;
        h = fast_tanh_pre(u);
    };

#pragma unroll 1
    for (int e = 0; e < TT / 16; ++e) {
        const int tB = e * 16 + 8;
#pragma unroll
        for (int t = 0; t < 8; ++t)
            pB[t] = __bfloat162float(gp[(size_t)(tB + t) * PSTRIDE]);
#pragma unroll
        for (int t = 0; t < 8; ++t) PIN(pA[t]);
#pragma unroll
        for (int s = 0; s < 8; ++s) step(pA[s]);

        int tA = e * 16 + 16;
        if (tA > TT - 8) tA = TT - 8;
#pragma unroll
        for (int t = 0; t < 8; ++t)
            pA[t] = __bfloat162float(gp[(size_t)(tA + t) * PSTRIDE]);
#pragma unroll
        for (int t = 0; t < 8; ++t) PIN(pB[t]);
#pragma unroll
        for (int s = 0; s < 8; ++s) step(pB[s]);
    }

    __shared__ float hf[64];
    hf[l] = h;
    if (l < 10) {
        const int rr = l / 5, c = l % 5;
        float acc = b_cls[c];
#pragma unroll
        for (int k = 0; k < 32; ++k)
            acc = fmaf(hf[rr * 32 + k], W_cls[k * 5 + c], acc);
        out[(blockIdx.x * 2 + rr) * 5 + c] = acc;
    }
}

// ---------------- Fallback (fused) for tiny workspace ----------------------------------
__device__ __forceinline__ float rnn_step_fb(const float4 xt[8], const float wx[32],
                                             const float wh[32], float bj,
                                             float* hrow, int lane) {
    float u0 = 0.f, u1 = 0.f, u2 = 0.f, u3 = 0.f;
#pragma unroll
    for (int q = 0; q < 8; ++q) {
        u0 = fmaf(xt[q].x, wx[4*q+0], u0);
        u1 = fmaf(xt[q].y, wx[4*q+1], u1);
        u2 = fmaf(xt[q].z, wx[4*q+2], u2);
        u3 = fmaf(xt[q].w, wx[4*q+3], u3);
    }
    const float4* hp = (const float4*)hrow;
#pragma unroll
    for (int q = 0; q < 8; ++q) {
        float4 hv = hp[q];
        u0 = fmaf(hv.x, wh[4*q+0], u0);
        u1 = fmaf(hv.y, wh[4*q+1], u1);
        u2 = fmaf(hv.z, wh[4*q+2], u2);
        u3 = fmaf(hv.w, wh[4*q+3], u3);
    }
    float hn = fast_tanh(bj + ((u0 + u1) + (u2 + u3)));
    hrow[lane] = hn;
    return hn;
}

__global__ __launch_bounds__(64, 1) void rnn_seq_kernel(
        const int* __restrict__ x, const float* __restrict__ emb,
        const float* __restrict__ W_rnn, const float* __restrict__ b_rnn,
        const float* __restrict__ W_cls, const float* __restrict__ b_cls,
        float* __restrict__ out) {
    const int lane = threadIdx.x & 31;
    const int grp  = threadIdx.x >> 5;
    const int row  = blockIdx.x * 2 + grp;
    __shared__ float hbuf[2][HH];
    float wx[32], wh[32];
#pragma unroll
    for (int k = 0; k < 32; ++k) {
        wx[k] = W_rnn[k * HH + lane];
        wh[k] = W_rnn[(HH + k) * HH + lane];
    }
    const float bj = b_rnn[lane];
    hbuf[grp][lane] = 0.0f;
    float* hrow = &hbuf[grp][0];
    int i1 = x[1 * BB + row];
    float4 xcur[8], xnxt[8];
    {
        int i0 = x[0 * BB + row];
        const float4* ep = (const float4*)(emb + (size_t)i0 * HH);
#pragma unroll
        for (int q = 0; q < 8; ++q) xcur[q] = ep[q];
    }
    for (int t = 0; t < TT; t += 2) {
        int i2 = x[min(t + 2, TT - 1) * BB + row];
        {
            const float4* ep = (const float4*)(emb + (size_t)i1 * HH);
#pragma unroll
            for (int q = 0; q < 8; ++q) xnxt[q] = ep[q];
        }
        rnn_step_fb(xcur, wx, wh, bj, hrow, lane);
        i1 = x[min(t + 3, TT - 1) * BB + row];
        {
            const float4* ep = (const float4*)(emb + (size_t)i2 * HH);
#pragma unroll
            for (int q = 0; q < 8; ++q) xcur[q] = ep[q];
        }
        rnn_step_fb(xnxt, wx, wh, bj, hrow, lane);
    }
    if (lane < 5) {
        float acc = b_cls[lane];
#pragma unroll
        for (int k = 0; k < 32; ++k)
            acc = fmaf(hrow[k], W_cls[k * 5 + lane], acc);
        out[row * 5 + lane] = acc;
    }
}

extern "C" void kernel_launch(void* const* d_in, const int* in_sizes, int n_in,
                              void* d_out, int out_size, void* d_ws, size_t ws_size,
                              hipStream_t stream) {
    const int*   x     = (const int*)d_in[0];
    const float* emb   = (const float*)d_in[1];
    const float* W_rnn = (const float*)d_in[2];
    const float* b_rnn = (const float*)d_in[3];
    const float* W_cls = (const float*)d_in[4];
    const float* b_cls = (const float*)d_in[5];
    float* out = (float*)d_out;

    const size_t need16 = (size_t)NPAIR * HH * 2;   // 64 MiB (bf16 P)
    if (ws_size >= need16) {
        __hip_bfloat16* P = (__hip_bfloat16*)d_ws;
        const int pre_blocks = NPAIR / (16 * 4);    // 16384 blocks x 256 thr (4 waves)
        precompute_mfma<<<pre_blocks, 256, 0, stream>>>(x, emb, W_rnn, b_rnn, P);
        rnn_seq_v13<<<BB / 2, 64, 0, stream>>>(P, W_rnn, W_cls, b_cls, out);
    } else {
        rnn_seq_kernel<<<BB / 2, 64, 0, stream>>>(x, emb, W_rnn, b_rnn, W_cls, b_cls, out);
    }
}

// Round 14
// 364.326 us; speedup vs baseline: 1.4836x; 1.0193x over previous
//
#include <hip/hip_runtime.h>
#include <hip/hip_bf16.h>

#define TT 2048
#define BB 512
#define HH 32
#define NPAIR (TT * BB)
#define PSTRIDE (BB * HH)   // elements per t-slice of P = 16384
#define CSC 2.88539008177792681f   // 2*log2(e), folded into W/b/P

// Pin a value into a live VGPR (R9-proven variant, no memory clobber).
#define PIN(x) asm volatile("" : "+v"(x))

// Inputs pre-scaled by CSC => tanh(u) = 1 - 2/(1+2^u'), u' = CSC*u arrives ready.
__device__ __forceinline__ float fast_tanh_pre(float u) {
    float e = exp2f(u);
    return fmaf(__builtin_amdgcn_rcpf(e + 1.0f), -2.0f, 1.0f);
}
// Unscaled variant for the fallback kernel.
__device__ __forceinline__ float fast_tanh(float u) {
    float e = exp2f(u * CSC);
    return fmaf(__builtin_amdgcn_rcpf(e + 1.0f), -2.0f, 1.0f);
}

// DPP row-rotate by N within each 16-lane row.
template <int N>
__device__ __forceinline__ float dpp_ror(float v) {
    return __int_as_float(__builtin_amdgcn_mov_dpp(
        __float_as_int(v), 0x120 | N, 0xF, 0xF, false));
}
// lane xor 16 within each 32-lane group (BitMode: xor=16, and=0x1F).
__device__ __forceinline__ float swz_x16(float v) {
    return __int_as_float(__builtin_amdgcn_ds_swizzle(__float_as_int(v), 0x401F));
}

__device__ __forceinline__ unsigned short f2bfu(float f) {
    __hip_bfloat16 h = __float2bfloat16(f);
    return *reinterpret_cast<unsigned short*>(&h);
}
__device__ __forceinline__ short f2bf(float f) {
    __hip_bfloat16 h = __float2bfloat16(f);
    return *reinterpret_cast<short*>(&h);
}

typedef __attribute__((ext_vector_type(8))) short bf16x8;
typedef __attribute__((ext_vector_type(4))) float f32x4;

// ---------------- Pass 1: MFMA precompute, swapped operands, 64 pairs/wave -------------
// D[m=j][n=pair]: A = CSC*Wx (setup ONCE per wave), B = gathered emb rows (per iter).
// C/D: col=lane&15 (pair), row=quad*4+reg (j) => lane's 4 regs are 4 consecutive j of
// one pair => 8-byte packed stores (R13's 8x2B scatter was the per-wave cost driver).
__global__ __launch_bounds__(256) void precompute_mfma2(
        const int* __restrict__ x, const float* __restrict__ emb,
        const float* __restrict__ W_rnn, const float* __restrict__ b_rnn,
        __hip_bfloat16* __restrict__ P) {
    const int l  = threadIdx.x & 63;
    const int wv = (blockIdx.x * 256 + threadIdx.x) >> 6;   // global wave id
    const int m16 = l & 15;
    const int q   = l >> 4;           // quad: k-slice base q*8, C-row base q*4
    const int pair0 = wv * 64;

    // A-frags (once): A[m=m16][k=q*8+j] = CSC * Wx[k][m16(+16)]
    bf16x8 a0, a1;
#pragma unroll
    for (int j = 0; j < 8; ++j) {
        a0[j] = f2bf(CSC * W_rnn[(q * 8 + j) * HH + m16]);
        a1[j] = f2bf(CSC * W_rnn[(q * 8 + j) * HH + m16 + 16]);
    }
    // Bias init (once): c0[reg] -> row q*4+reg, c1[reg] -> +16.
    f32x4 cb0, cb1;
#pragma unroll
    for (int reg = 0; reg < 4; ++reg) {
        cb0[reg] = CSC * b_rnn[q * 4 + reg];
        cb1[reg] = CSC * b_rnn[q * 4 + reg + 16];
    }

#pragma unroll
    for (int it = 0; it < 4; ++it) {
        const int pairB = pair0 + it * 16;
        // B-frag: lane m16 gathers pair (pairB+m16)'s k-slice [q*8 .. q*8+7].
        const int idx = x[pairB + m16];
        const float4* ep = (const float4*)(emb + (size_t)idx * HH + q * 8);
        float4 e0 = ep[0], e1 = ep[1];
        bf16x8 bf;
        bf[0] = f2bf(e0.x); bf[1] = f2bf(e0.y); bf[2] = f2bf(e0.z); bf[3] = f2bf(e0.w);
        bf[4] = f2bf(e1.x); bf[5] = f2bf(e1.y); bf[6] = f2bf(e1.z); bf[7] = f2bf(e1.w);

        f32x4 c0 = cb0, c1 = cb1;
        c0 = __builtin_amdgcn_mfma_f32_16x16x32_bf16(a0, bf, c0, 0, 0, 0);
        c1 = __builtin_amdgcn_mfma_f32_16x16x32_bf16(a1, bf, c1, 0, 0, 0);

        // Store: pair = pairB+m16, j = q*4+reg (+16). 4 consecutive bf16 -> uint2.
        uint2 s0, s1;
        s0.x = (unsigned)f2bfu(c0[0]) | ((unsigned)f2bfu(c0[1]) << 16);
        s0.y = (unsigned)f2bfu(c0[2]) | ((unsigned)f2bfu(c0[3]) << 16);
        s1.x = (unsigned)f2bfu(c1[0]) | ((unsigned)f2bfu(c1[1]) << 16);
        s1.y = (unsigned)f2bfu(c1[2]) | ((unsigned)f2bfu(c1[3]) << 16);
        __hip_bfloat16* pp = P + (size_t)(pairB + m16) * HH + q * 4;
        *(uint2*)(pp)      = s0;
        *(uint2*)(pp + 16) = s1;
    }
}

// ---------------- Pass 2: k-split scan (R13-exact; weights pre-scaled) -----------------
__global__ __launch_bounds__(64, 1) void rnn_seq_v13(
        const __hip_bfloat16* __restrict__ P, const float* __restrict__ W_rnn,
        const float* __restrict__ W_cls, const float* __restrict__ b_cls,
        float* __restrict__ out) {
    const int l = threadIdx.x;
    const int i = l & 15;
    const int q = (l >> 4) & 1;

    // Direction probe (validated R6-R13: absmax 0.0).
    int rt = __builtin_amdgcn_mov_dpp(i, 0x121, 0xF, 0xF, false);
    const int d = (rt == ((i + 1) & 15)) ? 1 : -1;

    float wKeep[16], wSend[16];
#pragma unroll
    for (int o = 0; o < 16; ++o) {
        const int k = q * 16 + ((i + d * o) & 15);
        wKeep[o] = CSC * W_rnn[(HH + k) * HH + (q * 16 + i)];
        wSend[o] = CSC * W_rnn[(HH + k) * HH + ((q ^ 1) * 16 + i)];
    }
#pragma unroll
    for (int o = 0; o < 16; ++o) { PIN(wKeep[o]); PIN(wSend[o]); }

    const __hip_bfloat16* gp = P + (size_t)blockIdx.x * 64 + l;

    float pA[8], pB[8];
#pragma unroll
    for (int t = 0; t < 8; ++t)
        pA[t] = __bfloat162float(gp[(size_t)t * PSTRIDE]);

    float h = 0.0f;

    auto step = [&](float p) {
        float rot[16];
        rot[0] = h;
        rot[1] = dpp_ror<1>(h);
        rot[2] = dpp_ror<2>(h);
        rot[3] = dpp_ror<3>(h);
#pragma unroll
        for (int m = 1; m < 4; ++m) {
            rot[4*m+0] = dpp_ror<4>(rot[4*m-4]);
            rot[4*m+1] = dpp_ror<4>(rot[4*m-3]);
            rot[4*m+2] = dpp_ror<4>(rot[4*m-2]);
            rot[4*m+3] = dpp_ror<4>(rot[4*m-1]);
        }
        float s0 = rot[0] * wSend[0], s1 = rot[1] * wSend[1];
        float s2 = rot[2] * wSend[2], s3 = rot[3] * wSend[3];
#pragma unroll
        for (int m = 1; m < 4; ++m) {
            s0 = fmaf(rot[4*m+0], wSend[4*m+0], s0);
            s1 = fmaf(rot[4*m+1], wSend[4*m+1], s1);
            s2 = fmaf(rot[4*m+2], wSend[4*m+2], s2);
            s3 = fmaf(rot[4*m+3], wSend[4*m+3], s3);
        }
        float send = (s0 + s1) + (s2 + s3);
        float recv = swz_x16(send);
        float k0 = fmaf(rot[0], wKeep[0], p), k1 = rot[1] * wKeep[1];
        float k2 = rot[2] * wKeep[2],         k3 = rot[3] * wKeep[3];
#pragma unroll
        for (int m = 1; m < 4; ++m) {
            k0 = fmaf(rot[4*m+0], wKeep[4*m+0], k0);
            k1 = fmaf(rot[4*m+1], wKeep[4*m+1], k1);
            k2 = fmaf(rot[4*m+2], wKeep[4*m+2], k2);
            k3 = fmaf(rot[4*m+3], wKeep[4*m+3], k3);
        }
        float u = ((k0 + k1) + (k2 + k3)) + recv;
        h = fast_tanh_pre(u);
    };

#pragma unroll 1
    for (int e = 0; e < TT / 16; ++e) {
        const int tB = e * 16 + 8;
#pragma unroll
        for (int t = 0; t < 8; ++t)
            pB[t] = __bfloat162float(gp[(size_t)(tB + t) * PSTRIDE]);
#pragma unroll
        for (int t = 0; t < 8; ++t) PIN(pA[t]);
#pragma unroll
        for (int s = 0; s < 8; ++s) step(pA[s]);

        int tA = e * 16 + 16;
        if (tA > TT - 8) tA = TT - 8;
#pragma unroll
        for (int t = 0; t < 8; ++t)
            pA[t] = __bfloat162float(gp[(size_t)(tA + t) * PSTRIDE]);
#pragma unroll
        for (int t = 0; t < 8; ++t) PIN(pB[t]);
#pragma unroll
        for (int s = 0; s < 8; ++s) step(pB[s]);
    }

    __shared__ float hf[64];
    hf[l] = h;
    if (l < 10) {
        const int rr = l / 5, c = l % 5;
        float acc = b_cls[c];
#pragma unroll
        for (int k = 0; k < 32; ++k)
            acc = fmaf(hf[rr * 32 + k], W_cls[k * 5 + c], acc);
        out[(blockIdx.x * 2 + rr) * 5 + c] = acc;
    }
}

// ---------------- Fallback (fused) for tiny workspace ----------------------------------
__device__ __forceinline__ float rnn_step_fb(const float4 xt[8], const float wx[32],
                                             const float wh[32], float bj,
                                             float* hrow, int lane) {
    float u0 = 0.f, u1 = 0.f, u2 = 0.f, u3 = 0.f;
#pragma unroll
    for (int q = 0; q < 8; ++q) {
        u0 = fmaf(xt[q].x, wx[4*q+0], u0);
        u1 = fmaf(xt[q].y, wx[4*q+1], u1);
        u2 = fmaf(xt[q].z, wx[4*q+2], u2);
        u3 = fmaf(xt[q].w, wx[4*q+3], u3);
    }
    const float4* hp = (const float4*)hrow;
#pragma unroll
    for (int q = 0; q < 8; ++q) {
        float4 hv = hp[q];
        u0 = fmaf(hv.x, wh[4*q+0], u0);
        u1 = fmaf(hv.y, wh[4*q+1], u1);
        u2 = fmaf(hv.z, wh[4*q+2], u2);
        u3 = fmaf(hv.w, wh[4*q+3], u3);
    }
    float hn = fast_tanh(bj + ((u0 + u1) + (u2 + u3)));
    hrow[lane] = hn;
    return hn;
}

__global__ __launch_bounds__(64, 1) void rnn_seq_kernel(
        const int* __restrict__ x, const float* __restrict__ emb,
        const float* __restrict__ W_rnn, const float* __restrict__ b_rnn,
        const float* __restrict__ W_cls, const float* __restrict__ b_cls,
        float* __restrict__ out) {
    const int lane = threadIdx.x & 31;
    const int grp  = threadIdx.x >> 5;
    const int row  = blockIdx.x * 2 + grp;
    __shared__ float hbuf[2][HH];
    float wx[32], wh[32];
#pragma unroll
    for (int k = 0; k < 32; ++k) {
        wx[k] = W_rnn[k * HH + lane];
        wh[k] = W_rnn[(HH + k) * HH + lane];
    }
    const float bj = b_rnn[lane];
    hbuf[grp][lane] = 0.0f;
    float* hrow = &hbuf[grp][0];
    int i1 = x[1 * BB + row];
    float4 xcur[8], xnxt[8];
    {
        int i0 = x[0 * BB + row];
        const float4* ep = (const float4*)(emb + (size_t)i0 * HH);
#pragma unroll
        for (int q = 0; q < 8; ++q) xcur[q] = ep[q];
    }
    for (int t = 0; t < TT; t += 2) {
        int i2 = x[min(t + 2, TT - 1) * BB + row];
        {
            const float4* ep = (const float4*)(emb + (size_t)i1 * HH);
#pragma unroll
            for (int q = 0; q < 8; ++q) xnxt[q] = ep[q];
        }
        rnn_step_fb(xcur, wx, wh, bj, hrow, lane);
        i1 = x[min(t + 3, TT - 1) * BB + row];
        {
            const float4* ep = (const float4*)(emb + (size_t)i2 * HH);
#pragma unroll
            for (int q = 0; q < 8; ++q) xcur[q] = ep[q];
        }
        rnn_step_fb(xnxt, wx, wh, bj, hrow, lane);
    }
    if (lane < 5) {
        float acc = b_cls[lane];
#pragma unroll
        for (int k = 0; k < 32; ++k)
            acc = fmaf(hrow[k], W_cls[k * 5 + lane], acc);
        out[row * 5 + lane] = acc;
    }
}

extern "C" void kernel_launch(void* const* d_in, const int* in_sizes, int n_in,
                              void* d_out, int out_size, void* d_ws, size_t ws_size,
                              hipStream_t stream) {
    const int*   x     = (const int*)d_in[0];
    const float* emb   = (const float*)d_in[1];
    const float* W_rnn = (const float*)d_in[2];
    const float* b_rnn = (const float*)d_in[3];
    const float* W_cls = (const float*)d_in[4];
    const float* b_cls = (const float*)d_in[5];
    float* out = (float*)d_out;

    const size_t need16 = (size_t)NPAIR * HH * 2;   // 64 MiB (bf16 P)
    if (ws_size >= need16) {
        __hip_bfloat16* P = (__hip_bfloat16*)d_ws;
        const int pre_blocks = NPAIR / 256;         // 4096 blocks x 4 waves x 64 pairs
        precompute_mfma2<<<pre_blocks, 256, 0, stream>>>(x, emb, W_rnn, b_rnn, P);
        rnn_seq_v13<<<BB / 2, 64, 0, stream>>>(P, W_rnn, W_cls, b_cls, out);
    } else {
        rnn_seq_kernel<<<BB / 2, 64, 0, stream>>>(x, emb, W_rnn, b_rnn, W_cls, b_cls, out);
    }
}